// Round 4
// baseline (771.995 us; speedup 1.0000x reference)
//
#include <hip/hip_runtime.h>
#include <hip/hip_bf16.h>

#define NN 50000
#define NE 800000
#define NG 64
#define SCAN_B 196   // 196*256 = 50176 >= NN

__device__ __forceinline__ float bf2f(unsigned short u){
    unsigned v = ((unsigned)u) << 16; float f; __builtin_memcpy(&f, &v, 4); return f;
}
__device__ __forceinline__ unsigned short f2bf(float f){
    unsigned u; __builtin_memcpy(&u, &f, 4);
    u = (u + 0x7fffu + ((u >> 16) & 1u)) >> 16;
    return (unsigned short)u;
}
__device__ __forceinline__ float lrelu(float v){ return v > 0.f ? v : 0.2f * v; }

__device__ __forceinline__ float ldflex(const void* p, long i, int isbf){
    if (isbf) return bf2f(((const unsigned short*)p)[i]);
    return ((const float*)p)[i];
}
__device__ __forceinline__ int ldidx(const int* p, long i, int is64){
    return p[is64 ? (i << 1) : i];
}

// ---------------- runtime dtype detection ----------------
__global__ void detect_kernel(const unsigned short* xu, const unsigned int* eiu,
                              const unsigned int* bu, int* flags){
    if (threadIdx.x != 0 || blockIdx.x != 0) return;
    int hit = 0;
    for (int i = 0; i < 128; i++){
        int ex = (xu[2 * i] >> 7) & 0xFF;
        if (ex >= 100 && ex <= 140) hit++;
    }
    flags[0] = (hit >= 64) ? 1 : 0;
    int z = 0;
    for (int i = 0; i < 128; i++) if (eiu[2 * i + 1] == 0) z++;
    flags[1] = (z >= 120) ? 1 : 0;
    z = 0;
    for (int i = 0; i < 128; i++) if (bu[49745 + 2 * i] == 0) z++;
    flags[2] = (z >= 120) ? 1 : 0;
}

// ---------------- CSR build ----------------
__global__ void count_kernel(const int* __restrict__ ei, int* __restrict__ counts,
                             const int* __restrict__ flags){
    int f64 = flags[1];
    int e = blockIdx.x * 256 + threadIdx.x;
    if (e < NE) atomicAdd(&counts[ldidx(ei, (long)NE + e, f64)], 1);
}

__global__ __launch_bounds__(256) void scan_part(const int* __restrict__ counts,
                                                 int* __restrict__ bsum){
    __shared__ int red[256];
    int tid = threadIdx.x;
    int i = blockIdx.x * 256 + tid;
    red[tid] = (i < NN) ? counts[i] : 0;
    __syncthreads();
    for (int s = 128; s > 0; s >>= 1){
        if (tid < s) red[tid] += red[tid + s];
        __syncthreads();
    }
    if (tid == 0) bsum[blockIdx.x] = red[0];
}

__global__ __launch_bounds__(256) void scan_mid(int* __restrict__ bsum){
    __shared__ int sd[256];
    int tid = threadIdx.x;
    int v = (tid < SCAN_B) ? bsum[tid] : 0;
    sd[tid] = v; __syncthreads();
    for (int off = 1; off < 256; off <<= 1){
        int x = sd[tid];
        int y = (tid >= off) ? sd[tid - off] : 0;
        __syncthreads();
        sd[tid] = x + y;
        __syncthreads();
    }
    if (tid < SCAN_B) bsum[tid] = sd[tid] - v;  // exclusive
}

__global__ __launch_bounds__(256) void scan_final(const int* __restrict__ counts,
                                                  const int* __restrict__ bsum,
                                                  int* __restrict__ row_ptr,
                                                  int* __restrict__ cursor){
    __shared__ int sd[256];
    int tid = threadIdx.x;
    int i = blockIdx.x * 256 + tid;
    int v = (i < NN) ? counts[i] : 0;
    sd[tid] = v; __syncthreads();
    for (int off = 1; off < 256; off <<= 1){
        int x = sd[tid];
        int y = (tid >= off) ? sd[tid - off] : 0;
        __syncthreads();
        sd[tid] = x + y;
        __syncthreads();
    }
    if (i < NN){
        int excl = sd[tid] - v + bsum[blockIdx.x];
        row_ptr[i] = excl;
        cursor[i] = excl;
    }
    if (i == 0) row_ptr[NN] = NE;  // total edges is a constant
}

__global__ void scatter_kernel(const int* __restrict__ ei,
                               int* __restrict__ cursor, int* __restrict__ csr,
                               int* __restrict__ dstc,
                               const int* __restrict__ flags){
    int f64 = flags[1];
    int e = blockIdx.x * 256 + threadIdx.x;
    if (e < NE){
        int d = ldidx(ei, (long)NE + e, f64);
        int s = ldidx(ei, (long)e, f64);
        int pos = atomicAdd(&cursor[d], 1);
        csr[pos] = s;
        dstc[pos] = d;
    }
}

// ---------------- fused GEMM + es/ed epilogue, bf16-packed h output -------
// hbf[n][96] (bf16) = in[n,K] @ W[K,96]; es/ed[n,H] from f32 accumulators.
template<int K, int H>
__global__ __launch_bounds__(256) void gemm_es_kernel(const void* __restrict__ in_,
                                                      const void* __restrict__ Wg,
                                                      const void* __restrict__ as_,
                                                      const void* __restrict__ ad_,
                                                      unsigned short* __restrict__ hbf,
                                                      float* __restrict__ es,
                                                      float* __restrict__ ed,
                                                      const int* __restrict__ flags,
                                                      int in_flex){
    constexpr int KC = 32;
    __shared__ float xs[KC][68];
    __shared__ float ws[KC][96];
    int isbf = flags[0];
    int inbf = in_flex ? isbf : 0;
    int tid = threadIdx.x;
    int row0 = blockIdx.x * 64;
    int tx = tid & 15, ty = tid >> 4;     // cols tx*6..+5, rows ty*4..+3
    float acc[4][6] = {};

    for (int k0 = 0; k0 < K; k0 += KC){
        {
            int r = tid >> 2, kb = (tid & 3) * 8;
            int rr = row0 + r; if (rr >= NN) rr = NN - 1;
            long base = (long)rr * K + k0 + kb;
            #pragma unroll
            for (int i = 0; i < 8; i++)
                xs[kb + i][r] = ldflex(in_, base + i, inbf);
        }
        for (int i = tid; i < KC * 96; i += 256){
            int kk = i / 96, cc = i - kk * 96;
            ws[kk][cc] = ldflex(Wg, (long)(k0 + kk) * 96 + cc, isbf);
        }
        __syncthreads();
        #pragma unroll 4
        for (int k = 0; k < KC; k++){
            float xr[4], wr[6];
            #pragma unroll
            for (int i = 0; i < 4; i++) xr[i] = xs[k][ty * 4 + i];
            #pragma unroll
            for (int j = 0; j < 6; j++) wr[j] = ws[k][tx * 6 + j];
            #pragma unroll
            for (int i = 0; i < 4; i++)
                #pragma unroll
                for (int j = 0; j < 6; j++)
                    acc[i][j] += xr[i] * wr[j];
        }
        __syncthreads();
    }

    float pes[4] = {}, ped[4] = {};
    #pragma unroll
    for (int j = 0; j < 6; j++){
        int c = tx * 6 + j;
        float av = ldflex(as_, c, isbf);
        float dv = ldflex(ad_, c, isbf);
        #pragma unroll
        for (int i = 0; i < 4; i++){ pes[i] += acc[i][j] * av; ped[i] += acc[i][j] * dv; }
    }
    constexpr int G = (H == 2) ? 8 : 16;
    for (int off = 1; off < G; off <<= 1){
        #pragma unroll
        for (int i = 0; i < 4; i++){
            pes[i] += __shfl_xor(pes[i], off);
            ped[i] += __shfl_xor(ped[i], off);
        }
    }
    unsigned int* hb32 = (unsigned int*)hbf;
    #pragma unroll
    for (int i = 0; i < 4; i++){
        int r = row0 + ty * 4 + i;
        if (r < NN){
            long o = (long)r * 48 + tx * 3;   // uint index (2 ch per uint)
            #pragma unroll
            for (int j = 0; j < 3; j++){
                unsigned int w = (unsigned int)f2bf(acc[i][2 * j])
                               | ((unsigned int)f2bf(acc[i][2 * j + 1]) << 16);
                hb32[o + j] = w;
            }
            if ((tx & (G - 1)) == 0){
                int hd = tx / G;
                es[(long)r * H + hd] = pes[i];
                ed[(long)r * H + hd] = ped[i];
            }
        }
    }
}

// ---------------- per-edge exp score ----------------
template<int H>
__global__ void pexp_kernel(const float* __restrict__ es, const float* __restrict__ ed,
                            const int* __restrict__ csr, const int* __restrict__ dstc,
                            float* __restrict__ pexp){
    int i = blockIdx.x * 256 + threadIdx.x;
    if (i >= NE) return;
    int s = csr[i], d = dstc[i];
    #pragma unroll
    for (int h = 0; h < H; h++)
        pexp[(long)i * H + h] = __expf(lrelu(es[(long)s * H + h] + ed[(long)d * H + h]));
}

// ---------------- attention: one wave per node, no barriers ----------------
// lane c<48 handles channels {2c, 2c+1} via one packed bf16x2 load.
template<int H>
__global__ __launch_bounds__(256) void attn_kernel(const unsigned short* __restrict__ hbf,
                                                   const float* __restrict__ pexp,
                                                   const float* __restrict__ es,
                                                   const float* __restrict__ ed,
                                                   const int* __restrict__ row_ptr,
                                                   const int* __restrict__ csr,
                                                   const void* __restrict__ bias,
                                                   float* __restrict__ out,
                                                   const int* __restrict__ flags){
    int lane = threadIdx.x & 63;
    int d = blockIdx.x * 4 + (threadIdx.x >> 6);
    if (d >= NN) return;
    int isbf = flags[0];
    int beg = row_ptr[d], deg = row_ptr[d + 1] - beg;
    int hd = (H == 2) ? (lane / 24) : 0;
    const unsigned int* hrow = (const unsigned int*)hbf;
    float acc0 = 0.f, acc1 = 0.f, dn = 0.f;
    #pragma unroll 4
    for (int j = 0; j < deg; j++){
        int s = csr[beg + j];                       // wave-uniform broadcast load
        float pj = pexp[(long)(beg + j) * H + hd];  // wave-uniform (per head)
        if (lane < 48){
            unsigned int v = hrow[(long)s * 48 + lane];
            acc0 += pj * bf2f((unsigned short)v);
            acc1 += pj * bf2f((unsigned short)(v >> 16));
            dn += pj;
        }
    }
    if (lane < 48){
        float ps = __expf(lrelu(es[(long)d * H + hd] + ed[(long)d * H + hd]));
        unsigned int v = hrow[(long)d * 48 + lane];
        acc0 += ps * bf2f((unsigned short)v);
        acc1 += ps * bf2f((unsigned short)(v >> 16));
        dn += ps;
        int c0 = 2 * lane;
        float o0 = acc0 / dn + ldflex(bias, c0, isbf);
        float o1 = acc1 / dn + ldflex(bias, c0 + 1, isbf);
        float2 o; o.x = fmaxf(o0, 0.f); o.y = fmaxf(o1, 0.f);
        ((float2*)out)[(long)d * 48 + lane] = o;
    }
}

// ---------------- pooling ----------------
__global__ __launch_bounds__(128) void pool_kernel(const float* __restrict__ in,
                                                   const int* __restrict__ batch,
                                                   float* __restrict__ pooled,
                                                   int* __restrict__ gcnt,
                                                   const int* __restrict__ flags){
    int f64 = flags[2];
    int n0 = blockIdx.x * 128;
    if (n0 >= NN) return;
    int n1 = n0 + 128; if (n1 > NN) n1 = NN;
    int tid = threadIdx.x;
    if (tid < 96){
        int c = tid;
        float acc = 0.f;
        int curg = ldidx(batch, n0, f64);
        for (int nd = n0; nd < n1; nd++){
            int g = ldidx(batch, nd, f64);
            if (g != curg){
                atomicAdd(&pooled[curg * 96 + c], acc);
                acc = 0.f; curg = g;
            }
            acc += in[(long)nd * 96 + c];
        }
        atomicAdd(&pooled[curg * 96 + c], acc);
    } else if (tid == 96){
        int cnt = 0;
        int curg = ldidx(batch, n0, f64);
        for (int nd = n0; nd < n1; nd++){
            int g = ldidx(batch, nd, f64);
            if (g != curg){
                atomicAdd(&gcnt[curg], cnt);
                cnt = 0; curg = g;
            }
            cnt++;
        }
        atomicAdd(&gcnt[curg], cnt);
    }
}

__global__ void final_kernel(const float* __restrict__ pooled, const int* __restrict__ gcnt,
                             const void* __restrict__ Wc, const void* __restrict__ bc,
                             void* __restrict__ outp, const int* __restrict__ flags){
    int isbf = flags[0];
    int g = threadIdx.x;
    if (g >= NG) return;
    float cnt = (float)gcnt[g];
    if (cnt < 1.f) cnt = 1.f;
    float acc = 0.f;
    for (int c = 0; c < 96; c++)
        acc += (pooled[g * 96 + c] / cnt) * ldflex(Wc, c, isbf);
    acc += ldflex(bc, 0, isbf);
    float sg = 1.f / (1.f + __expf(-acc));
    if (isbf) ((unsigned short*)outp)[g] = f2bf(sg);
    else      ((float*)outp)[g] = sg;
}

extern "C" void kernel_launch(void* const* d_in, const int* in_sizes, int n_in,
                              void* d_out, int out_size, void* d_ws, size_t ws_size,
                              hipStream_t stream){
    const void* x     = d_in[0];
    const int* ei     = (const int*)d_in[1];
    const int* batch  = (const int*)d_in[3];
    const void* W[4]  = {d_in[4],  d_in[8],  d_in[12], d_in[16]};
    const void* AS[4] = {d_in[5],  d_in[9],  d_in[13], d_in[17]};
    const void* AD[4] = {d_in[6],  d_in[10], d_in[14], d_in[18]};
    const void* B[4]  = {d_in[7],  d_in[11], d_in[15], d_in[19]};
    const void* Wc    = d_in[20];
    const void* bc    = d_in[21];

    char* p = (char*)d_ws;
    auto alloc = [&](size_t bytes) -> void* {
        void* r = (void*)p;
        p += (bytes + 255) & ~(size_t)255;
        return r;
    };
    int* flags     = (int*)alloc(16);
    unsigned short* hbf = (unsigned short*)alloc((size_t)NN * 96 * 2);  // bf16 h
    float* buf1    = (float*)alloc((size_t)NN * 96 * 4);                // attn out (f32)
    float* es      = (float*)alloc((size_t)NN * 2 * 4);
    float* ed      = (float*)alloc((size_t)NN * 2 * 4);
    float* pexp    = (float*)alloc((size_t)NE * 2 * 4);
    int* counts    = (int*)alloc((size_t)NN * 4);
    int* row_ptr   = (int*)alloc((size_t)(NN + 1) * 4);
    int* cursor    = (int*)alloc((size_t)NN * 4);
    int* csr       = (int*)alloc((size_t)NE * 4);
    int* dstc      = (int*)alloc((size_t)NE * 4);
    int* bsum      = (int*)alloc((size_t)SCAN_B * 4);
    float* pooled  = (float*)alloc((size_t)NG * 96 * 4);
    int* gcnt      = (int*)alloc((size_t)NG * 4);

    detect_kernel<<<1, 64, 0, stream>>>((const unsigned short*)x, (const unsigned int*)ei,
                                        (const unsigned int*)batch, flags);

    // CSR build (by dst), reused across layers
    hipMemsetAsync(counts, 0, (size_t)NN * 4, stream);
    count_kernel<<<(NE + 255) / 256, 256, 0, stream>>>(ei, counts, flags);
    scan_part<<<SCAN_B, 256, 0, stream>>>(counts, bsum);
    scan_mid<<<1, 256, 0, stream>>>(bsum);
    scan_final<<<SCAN_B, 256, 0, stream>>>(counts, bsum, row_ptr, cursor);
    scatter_kernel<<<(NE + 255) / 256, 256, 0, stream>>>(ei, cursor, csr, dstc, flags);

    const int GB = (NN + 63) / 64;        // 782
    const int AB = (NN + 3) / 4;          // 12500
    const int EB = (NE + 255) / 256;      // 3125

    // layer 1 (H=2, K=128, input may be bf16-flex)
    gemm_es_kernel<128, 2><<<GB, 256, 0, stream>>>(x, W[0], AS[0], AD[0], hbf, es, ed, flags, 1);
    pexp_kernel<2><<<EB, 256, 0, stream>>>(es, ed, csr, dstc, pexp);
    attn_kernel<2><<<AB, 256, 0, stream>>>(hbf, pexp, es, ed, row_ptr, csr, B[0], buf1, flags);
    // layers 2..4 (H=1, K=96)
    for (int l = 1; l < 4; l++){
        gemm_es_kernel<96, 1><<<GB, 256, 0, stream>>>(buf1, W[l], AS[l], AD[l], hbf, es, ed, flags, 0);
        pexp_kernel<1><<<EB, 256, 0, stream>>>(es, ed, csr, dstc, pexp);
        attn_kernel<1><<<AB, 256, 0, stream>>>(hbf, pexp, es, ed, row_ptr, csr, B[l], buf1, flags);
    }

    hipMemsetAsync(pooled, 0, (size_t)NG * 96 * 4, stream);
    hipMemsetAsync(gcnt, 0, (size_t)NG * 4, stream);
    pool_kernel<<<(NN + 127) / 128, 128, 0, stream>>>(buf1, batch, pooled, gcnt, flags);
    final_kernel<<<1, 64, 0, stream>>>(pooled, gcnt, Wc, bc, d_out, flags);
}

// Round 5
// 629.056 us; speedup vs baseline: 1.2272x; 1.2272x over previous
//
#include <hip/hip_runtime.h>
#include <hip/hip_bf16.h>

#define NN 50000
#define NE 800000
#define NG 64
#define SCAN_B 196   // 196*256 = 50176 >= NN

__device__ __forceinline__ float bf2f(unsigned short u){
    unsigned v = ((unsigned)u) << 16; float f; __builtin_memcpy(&f, &v, 4); return f;
}
__device__ __forceinline__ unsigned short f2bf(float f){
    unsigned u; __builtin_memcpy(&u, &f, 4);
    u = (u + 0x7fffu + ((u >> 16) & 1u)) >> 16;
    return (unsigned short)u;
}
__device__ __forceinline__ float lrelu(float v){ return v > 0.f ? v : 0.2f * v; }

__device__ __forceinline__ float ldflex(const void* p, long i, int isbf){
    if (isbf) return bf2f(((const unsigned short*)p)[i]);
    return ((const float*)p)[i];
}
__device__ __forceinline__ int ldidx(const int* p, long i, int is64){
    return p[is64 ? (i << 1) : i];
}

// ---------------- runtime dtype detection ----------------
__global__ void detect_kernel(const unsigned short* xu, const unsigned int* eiu,
                              const unsigned int* bu, int* flags){
    if (threadIdx.x != 0 || blockIdx.x != 0) return;
    int hit = 0;
    for (int i = 0; i < 128; i++){
        int ex = (xu[2 * i] >> 7) & 0xFF;
        if (ex >= 100 && ex <= 140) hit++;
    }
    flags[0] = (hit >= 64) ? 1 : 0;
    int z = 0;
    for (int i = 0; i < 128; i++) if (eiu[2 * i + 1] == 0) z++;
    flags[1] = (z >= 120) ? 1 : 0;
    z = 0;
    for (int i = 0; i < 128; i++) if (bu[49745 + 2 * i] == 0) z++;
    flags[2] = (z >= 120) ? 1 : 0;
}

// ---------------- CSR build ----------------
__global__ void count_kernel(const int* __restrict__ ei, int* __restrict__ counts,
                             const int* __restrict__ flags){
    int f64 = flags[1];
    int e = blockIdx.x * 256 + threadIdx.x;
    if (e < NE) atomicAdd(&counts[ldidx(ei, (long)NE + e, f64)], 1);
}

__global__ __launch_bounds__(256) void scan_part(const int* __restrict__ counts,
                                                 int* __restrict__ bsum){
    __shared__ int red[256];
    int tid = threadIdx.x;
    int i = blockIdx.x * 256 + tid;
    red[tid] = (i < NN) ? counts[i] : 0;
    __syncthreads();
    for (int s = 128; s > 0; s >>= 1){
        if (tid < s) red[tid] += red[tid + s];
        __syncthreads();
    }
    if (tid == 0) bsum[blockIdx.x] = red[0];
}

__global__ __launch_bounds__(256) void scan_mid(int* __restrict__ bsum){
    __shared__ int sd[256];
    int tid = threadIdx.x;
    int v = (tid < SCAN_B) ? bsum[tid] : 0;
    sd[tid] = v; __syncthreads();
    for (int off = 1; off < 256; off <<= 1){
        int x = sd[tid];
        int y = (tid >= off) ? sd[tid - off] : 0;
        __syncthreads();
        sd[tid] = x + y;
        __syncthreads();
    }
    if (tid < SCAN_B) bsum[tid] = sd[tid] - v;  // exclusive
}

__global__ __launch_bounds__(256) void scan_final(const int* __restrict__ counts,
                                                  const int* __restrict__ bsum,
                                                  int* __restrict__ row_ptr,
                                                  int* __restrict__ cursor){
    __shared__ int sd[256];
    int tid = threadIdx.x;
    int i = blockIdx.x * 256 + tid;
    int v = (i < NN) ? counts[i] : 0;
    sd[tid] = v; __syncthreads();
    for (int off = 1; off < 256; off <<= 1){
        int x = sd[tid];
        int y = (tid >= off) ? sd[tid - off] : 0;
        __syncthreads();
        sd[tid] = x + y;
        __syncthreads();
    }
    if (i < NN){
        int excl = sd[tid] - v + bsum[blockIdx.x];
        row_ptr[i] = excl;
        cursor[i] = excl;
    }
    if (i == 0) row_ptr[NN] = NE;
}

__global__ void scatter_kernel(const int* __restrict__ ei,
                               int* __restrict__ cursor, int* __restrict__ csr,
                               const int* __restrict__ flags){
    int f64 = flags[1];
    int e = blockIdx.x * 256 + threadIdx.x;
    if (e < NE){
        int d = ldidx(ei, (long)NE + e, f64);
        int s = ldidx(ei, (long)e, f64);
        int pos = atomicAdd(&cursor[d], 1);
        csr[pos] = s;
    }
}

// ---------------- fused GEMM + es/ed epilogue, bf16-packed h output -------
template<int K, int H>
__global__ __launch_bounds__(256) void gemm_es_kernel(const void* __restrict__ in_,
                                                      const void* __restrict__ Wg,
                                                      const void* __restrict__ as_,
                                                      const void* __restrict__ ad_,
                                                      unsigned short* __restrict__ hbf,
                                                      float* __restrict__ es,
                                                      float* __restrict__ ed,
                                                      const int* __restrict__ flags,
                                                      int in_flex){
    constexpr int KC = 32;
    __shared__ float xs[KC][68];
    __shared__ float ws[KC][96];
    int isbf = flags[0];
    int inbf = in_flex ? isbf : 0;
    int tid = threadIdx.x;
    int row0 = blockIdx.x * 64;
    int tx = tid & 15, ty = tid >> 4;     // cols tx*6..+5, rows ty*4..+3
    float acc[4][6] = {};

    for (int k0 = 0; k0 < K; k0 += KC){
        {
            int r = tid >> 2, kb = (tid & 3) * 8;
            int rr = row0 + r; if (rr >= NN) rr = NN - 1;
            long base = (long)rr * K + k0 + kb;
            #pragma unroll
            for (int i = 0; i < 8; i++)
                xs[kb + i][r] = ldflex(in_, base + i, inbf);
        }
        for (int i = tid; i < KC * 96; i += 256){
            int kk = i / 96, cc = i - kk * 96;
            ws[kk][cc] = ldflex(Wg, (long)(k0 + kk) * 96 + cc, isbf);
        }
        __syncthreads();
        #pragma unroll 4
        for (int k = 0; k < KC; k++){
            float xr[4], wr[6];
            #pragma unroll
            for (int i = 0; i < 4; i++) xr[i] = xs[k][ty * 4 + i];
            #pragma unroll
            for (int j = 0; j < 6; j++) wr[j] = ws[k][tx * 6 + j];
            #pragma unroll
            for (int i = 0; i < 4; i++)
                #pragma unroll
                for (int j = 0; j < 6; j++)
                    acc[i][j] += xr[i] * wr[j];
        }
        __syncthreads();
    }

    float pes[4] = {}, ped[4] = {};
    #pragma unroll
    for (int j = 0; j < 6; j++){
        int c = tx * 6 + j;
        float av = ldflex(as_, c, isbf);
        float dv = ldflex(ad_, c, isbf);
        #pragma unroll
        for (int i = 0; i < 4; i++){ pes[i] += acc[i][j] * av; ped[i] += acc[i][j] * dv; }
    }
    constexpr int G = (H == 2) ? 8 : 16;
    for (int off = 1; off < G; off <<= 1){
        #pragma unroll
        for (int i = 0; i < 4; i++){
            pes[i] += __shfl_xor(pes[i], off);
            ped[i] += __shfl_xor(ped[i], off);
        }
    }
    unsigned int* hb32 = (unsigned int*)hbf;
    #pragma unroll
    for (int i = 0; i < 4; i++){
        int r = row0 + ty * 4 + i;
        if (r < NN){
            long o = (long)r * 48 + tx * 3;
            #pragma unroll
            for (int j = 0; j < 3; j++){
                unsigned int w = (unsigned int)f2bf(acc[i][2 * j])
                               | ((unsigned int)f2bf(acc[i][2 * j + 1]) << 16);
                hb32[o + j] = w;
            }
            if ((tx & (G - 1)) == 0){
                int hd = tx / G;
                es[(long)r * H + hd] = pes[i];
                ed[(long)r * H + hd] = ped[i];
            }
        }
    }
}

// ---------------- attention: wave per node ----------------
// lanes 48-63: metadata pipeline (csr + es gather + exp), 16-edge batches,
// double-buffered one batch ahead. lanes 0-47: 16 gathers in flight, then FMA.
template<int H>
__global__ __launch_bounds__(256) void attn_kernel(const unsigned short* __restrict__ hbf,
                                                   const float* __restrict__ es,
                                                   const float* __restrict__ ed,
                                                   const int* __restrict__ row_ptr,
                                                   const int* __restrict__ csr,
                                                   const void* __restrict__ bias,
                                                   float* __restrict__ out,
                                                   const int* __restrict__ flags){
    int lane = threadIdx.x & 63;
    int d = blockIdx.x * 4 + (threadIdx.x >> 6);
    if (d >= NN) return;
    int isbf = flags[0];
    int beg = row_ptr[d], deg = row_ptr[d + 1] - beg;
    float edd0 = ed[(long)d * H];
    float edd1 = (H == 2) ? ed[(long)d * H + 1] : edd0;
    const unsigned int* hrow = (const unsigned int*)hbf;
    int m = lane - 48;

    // prefetch batch 0 metadata (lanes 48-63)
    int s_nxt = 0; float p0_nxt = 0.f, p1_nxt = 0.f;
    if (lane >= 48 && m < deg){
        int sj = csr[beg + m];
        s_nxt = sj;
        p0_nxt = __expf(lrelu(es[(long)sj * H] + edd0));
        if (H == 2) p1_nxt = __expf(lrelu(es[(long)sj * H + 1] + edd1));
    }

    float acc0 = 0.f, acc1 = 0.f, dn = 0.f;
    for (int base = 0; base < deg; base += 16){
        int cnt = deg - base; if (cnt > 16) cnt = 16;
        int s_cur = s_nxt; float p0c = p0_nxt, p1c = p1_nxt;
        int nb = base + 16;
        if (lane >= 48 && nb + m < deg){
            int sj = csr[beg + nb + m];
            s_nxt = sj;
            p0_nxt = __expf(lrelu(es[(long)sj * H] + edd0));
            if (H == 2) p1_nxt = __expf(lrelu(es[(long)sj * H + 1] + edd1));
        }
        unsigned int v[16]; float pp[16];
        #pragma unroll
        for (int j = 0; j < 16; j++){
            int s = __shfl(s_cur, 48 + j);
            float p0 = __shfl(p0c, 48 + j);
            float p = p0;
            if (H == 2){
                float p1 = __shfl(p1c, 48 + j);
                p = (lane < 24) ? p0 : p1;
            }
            bool inb = (j < cnt);
            pp[j] = inb ? p : 0.f;
            v[j] = (inb && lane < 48) ? hrow[(unsigned)s * 48u + (unsigned)lane] : 0u;
        }
        #pragma unroll
        for (int j = 0; j < 16; j++){
            float p = pp[j];
            acc0 += p * bf2f((unsigned short)v[j]);
            acc1 += p * bf2f((unsigned short)(v[j] >> 16));
            dn += p;
        }
    }

    if (lane < 48){
        int hd = (H == 2) ? (lane / 24) : 0;
        float ps = __expf(lrelu(es[(long)d * H + hd] + ed[(long)d * H + hd]));
        unsigned int v = hrow[(unsigned)d * 48u + (unsigned)lane];
        acc0 += ps * bf2f((unsigned short)v);
        acc1 += ps * bf2f((unsigned short)(v >> 16));
        dn += ps;
        int c0 = 2 * lane;
        float o0 = acc0 / dn + ldflex(bias, c0, isbf);
        float o1 = acc1 / dn + ldflex(bias, c0 + 1, isbf);
        float2 o; o.x = fmaxf(o0, 0.f); o.y = fmaxf(o1, 0.f);
        ((float2*)out)[(long)d * 48 + lane] = o;
    }
}

// ---------------- pooling ----------------
__global__ __launch_bounds__(128) void pool_kernel(const float* __restrict__ in,
                                                   const int* __restrict__ batch,
                                                   float* __restrict__ pooled,
                                                   int* __restrict__ gcnt,
                                                   const int* __restrict__ flags){
    int f64 = flags[2];
    int n0 = blockIdx.x * 128;
    if (n0 >= NN) return;
    int n1 = n0 + 128; if (n1 > NN) n1 = NN;
    int tid = threadIdx.x;
    if (tid < 96){
        int c = tid;
        float acc = 0.f;
        int curg = ldidx(batch, n0, f64);
        for (int nd = n0; nd < n1; nd++){
            int g = ldidx(batch, nd, f64);
            if (g != curg){
                atomicAdd(&pooled[curg * 96 + c], acc);
                acc = 0.f; curg = g;
            }
            acc += in[(long)nd * 96 + c];
        }
        atomicAdd(&pooled[curg * 96 + c], acc);
    } else if (tid == 96){
        int cnt = 0;
        int curg = ldidx(batch, n0, f64);
        for (int nd = n0; nd < n1; nd++){
            int g = ldidx(batch, nd, f64);
            if (g != curg){
                atomicAdd(&gcnt[curg], cnt);
                cnt = 0; curg = g;
            }
            cnt++;
        }
        atomicAdd(&gcnt[curg], cnt);
    }
}

__global__ void final_kernel(const float* __restrict__ pooled, const int* __restrict__ gcnt,
                             const void* __restrict__ Wc, const void* __restrict__ bc,
                             void* __restrict__ outp, const int* __restrict__ flags){
    int isbf = flags[0];
    int g = threadIdx.x;
    if (g >= NG) return;
    float cnt = (float)gcnt[g];
    if (cnt < 1.f) cnt = 1.f;
    float acc = 0.f;
    for (int c = 0; c < 96; c++)
        acc += (pooled[g * 96 + c] / cnt) * ldflex(Wc, c, isbf);
    acc += ldflex(bc, 0, isbf);
    float sg = 1.f / (1.f + __expf(-acc));
    if (isbf) ((unsigned short*)outp)[g] = f2bf(sg);
    else      ((float*)outp)[g] = sg;
}

extern "C" void kernel_launch(void* const* d_in, const int* in_sizes, int n_in,
                              void* d_out, int out_size, void* d_ws, size_t ws_size,
                              hipStream_t stream){
    const void* x     = d_in[0];
    const int* ei     = (const int*)d_in[1];
    const int* batch  = (const int*)d_in[3];
    const void* W[4]  = {d_in[4],  d_in[8],  d_in[12], d_in[16]};
    const void* AS[4] = {d_in[5],  d_in[9],  d_in[13], d_in[17]};
    const void* AD[4] = {d_in[6],  d_in[10], d_in[14], d_in[18]};
    const void* B[4]  = {d_in[7],  d_in[11], d_in[15], d_in[19]};
    const void* Wc    = d_in[20];
    const void* bc    = d_in[21];

    char* p = (char*)d_ws;
    auto alloc = [&](size_t bytes) -> void* {
        void* r = (void*)p;
        p += (bytes + 255) & ~(size_t)255;
        return r;
    };
    int* flags     = (int*)alloc(16);
    unsigned short* hbf = (unsigned short*)alloc((size_t)NN * 96 * 2);  // bf16 h
    float* buf1    = (float*)alloc((size_t)NN * 96 * 4);                // attn out (f32)
    float* es      = (float*)alloc((size_t)NN * 2 * 4);
    float* ed      = (float*)alloc((size_t)NN * 2 * 4);
    int* counts    = (int*)alloc((size_t)NN * 4);
    int* row_ptr   = (int*)alloc((size_t)(NN + 1) * 4);
    int* cursor    = (int*)alloc((size_t)NN * 4);
    int* csr       = (int*)alloc((size_t)NE * 4);
    int* bsum      = (int*)alloc((size_t)SCAN_B * 4);
    float* pooled  = (float*)alloc((size_t)NG * 96 * 4);
    int* gcnt      = (int*)alloc((size_t)NG * 4);

    detect_kernel<<<1, 64, 0, stream>>>((const unsigned short*)x, (const unsigned int*)ei,
                                        (const unsigned int*)batch, flags);

    // CSR build (by dst), reused across layers
    hipMemsetAsync(counts, 0, (size_t)NN * 4, stream);
    count_kernel<<<(NE + 255) / 256, 256, 0, stream>>>(ei, counts, flags);
    scan_part<<<SCAN_B, 256, 0, stream>>>(counts, bsum);
    scan_mid<<<1, 256, 0, stream>>>(bsum);
    scan_final<<<SCAN_B, 256, 0, stream>>>(counts, bsum, row_ptr, cursor);
    scatter_kernel<<<(NE + 255) / 256, 256, 0, stream>>>(ei, cursor, csr, flags);

    const int GB = (NN + 63) / 64;        // 782
    const int AB = (NN + 3) / 4;          // 12500

    // layer 1 (H=2, K=128, input may be bf16-flex)
    gemm_es_kernel<128, 2><<<GB, 256, 0, stream>>>(x, W[0], AS[0], AD[0], hbf, es, ed, flags, 1);
    attn_kernel<2><<<AB, 256, 0, stream>>>(hbf, es, ed, row_ptr, csr, B[0], buf1, flags);
    // layers 2..4 (H=1, K=96)
    for (int l = 1; l < 4; l++){
        gemm_es_kernel<96, 1><<<GB, 256, 0, stream>>>(buf1, W[l], AS[l], AD[l], hbf, es, ed, flags, 0);
        attn_kernel<1><<<AB, 256, 0, stream>>>(hbf, es, ed, row_ptr, csr, B[l], buf1, flags);
    }

    hipMemsetAsync(pooled, 0, (size_t)NG * 96 * 4, stream);
    hipMemsetAsync(gcnt, 0, (size_t)NG * 4, stream);
    pool_kernel<<<(NN + 127) / 128, 128, 0, stream>>>(buf1, batch, pooled, gcnt, flags);
    final_kernel<<<1, 64, 0, stream>>>(pooled, gcnt, Wc, bc, d_out, flags);
}

// Round 6
// 583.352 us; speedup vs baseline: 1.3234x; 1.0783x over previous
//
#include <hip/hip_runtime.h>
#include <hip/hip_bf16.h>

#define NN 50000
#define NE 800000
#define NG 64
#define SCAN_B 196   // 196*256 = 50176 >= NN

__device__ __forceinline__ float bf2f(unsigned short u){
    unsigned v = ((unsigned)u) << 16; float f; __builtin_memcpy(&f, &v, 4); return f;
}
__device__ __forceinline__ unsigned short f2bf(float f){
    unsigned u; __builtin_memcpy(&u, &f, 4);
    u = (u + 0x7fffu + ((u >> 16) & 1u)) >> 16;
    return (unsigned short)u;
}
__device__ __forceinline__ float lrelu(float v){ return v > 0.f ? v : 0.2f * v; }

__device__ __forceinline__ float ldflex(const void* p, long i, int isbf){
    if (isbf) return bf2f(((const unsigned short*)p)[i]);
    return ((const float*)p)[i];
}
__device__ __forceinline__ int ldidx(const int* p, long i, int is64){
    return p[is64 ? (i << 1) : i];
}

// ---- fp8 e4m3fn (OCP) pack/unpack, HW cvt when available ----
__device__ __forceinline__ unsigned int enc_fp8_1(float f){
    // manual e4m3fn encode (RNE, saturate to 448, subnormal-correct via 2^-120 scale)
    unsigned u; __builtin_memcpy(&u, &f, 4);
    unsigned s = (u >> 24) & 0x80u;
    float a = fabsf(f); a = fminf(a, 448.f);
    float x = a * 0x1p-120f;
    unsigned xu; __builtin_memcpy(&xu, &x, 4);
    unsigned r = (xu + 0x7FFFFu + ((xu >> 20) & 1u)) >> 20;
    if (r > 0x7Eu) r = 0x7Eu;
    return s | r;
}
__device__ __forceinline__ unsigned short pk_fp8(float a, float b){
#if __has_builtin(__builtin_amdgcn_cvt_pk_fp8_f32)
    int r = __builtin_amdgcn_cvt_pk_fp8_f32(a, b, 0, false);
    return (unsigned short)(r & 0xFFFF);
#else
    return (unsigned short)(enc_fp8_1(a) | (enc_fp8_1(b) << 8));
#endif
}
__device__ __forceinline__ float dec_fp8_manual(unsigned int byte){
    unsigned bits = ((byte & 0x80u) << 24) | ((byte & 0x7Fu) << 20);
    float f; __builtin_memcpy(&f, &bits, 4);
    return f * 0x1p120f;
}
__device__ __forceinline__ void dec_fp8x4(unsigned int v, float* o){
#if __has_builtin(__builtin_amdgcn_cvt_f32_fp8)
    o[0] = __builtin_amdgcn_cvt_f32_fp8((int)v, 0);
    o[1] = __builtin_amdgcn_cvt_f32_fp8((int)v, 1);
    o[2] = __builtin_amdgcn_cvt_f32_fp8((int)v, 2);
    o[3] = __builtin_amdgcn_cvt_f32_fp8((int)v, 3);
#else
    o[0] = dec_fp8_manual(v & 0xFF);
    o[1] = dec_fp8_manual((v >> 8) & 0xFF);
    o[2] = dec_fp8_manual((v >> 16) & 0xFF);
    o[3] = dec_fp8_manual((v >> 24) & 0xFF);
#endif
}

__device__ __forceinline__ int rdlane_i(int v, int l){ return __builtin_amdgcn_readlane(v, l); }
__device__ __forceinline__ float rdlane_f(float v, int l){
    int i; __builtin_memcpy(&i, &v, 4);
    int r = __builtin_amdgcn_readlane(i, l);
    float f; __builtin_memcpy(&f, &r, 4);
    return f;
}

// ---------------- runtime dtype detection ----------------
__global__ void detect_kernel(const unsigned short* xu, const unsigned int* eiu,
                              const unsigned int* bu, int* flags){
    if (threadIdx.x != 0 || blockIdx.x != 0) return;
    int hit = 0;
    for (int i = 0; i < 128; i++){
        int ex = (xu[2 * i] >> 7) & 0xFF;
        if (ex >= 100 && ex <= 140) hit++;
    }
    flags[0] = (hit >= 64) ? 1 : 0;
    int z = 0;
    for (int i = 0; i < 128; i++) if (eiu[2 * i + 1] == 0) z++;
    flags[1] = (z >= 120) ? 1 : 0;
    z = 0;
    for (int i = 0; i < 128; i++) if (bu[49745 + 2 * i] == 0) z++;
    flags[2] = (z >= 120) ? 1 : 0;
}

// ---------------- CSR build ----------------
__global__ void count_kernel(const int* __restrict__ ei, int* __restrict__ counts,
                             const int* __restrict__ flags){
    int f64 = flags[1];
    int e = blockIdx.x * 256 + threadIdx.x;
    if (e < NE) atomicAdd(&counts[ldidx(ei, (long)NE + e, f64)], 1);
}

__global__ __launch_bounds__(256) void scan_part(const int* __restrict__ counts,
                                                 int* __restrict__ bsum){
    __shared__ int red[256];
    int tid = threadIdx.x;
    int i = blockIdx.x * 256 + tid;
    red[tid] = (i < NN) ? counts[i] : 0;
    __syncthreads();
    for (int s = 128; s > 0; s >>= 1){
        if (tid < s) red[tid] += red[tid + s];
        __syncthreads();
    }
    if (tid == 0) bsum[blockIdx.x] = red[0];
}

__global__ __launch_bounds__(256) void scan_mid(int* __restrict__ bsum){
    __shared__ int sd[256];
    int tid = threadIdx.x;
    int v = (tid < SCAN_B) ? bsum[tid] : 0;
    sd[tid] = v; __syncthreads();
    for (int off = 1; off < 256; off <<= 1){
        int x = sd[tid];
        int y = (tid >= off) ? sd[tid - off] : 0;
        __syncthreads();
        sd[tid] = x + y;
        __syncthreads();
    }
    if (tid < SCAN_B) bsum[tid] = sd[tid] - v;  // exclusive
}

__global__ __launch_bounds__(256) void scan_final(const int* __restrict__ counts,
                                                  const int* __restrict__ bsum,
                                                  int* __restrict__ row_ptr,
                                                  int* __restrict__ cursor){
    __shared__ int sd[256];
    int tid = threadIdx.x;
    int i = blockIdx.x * 256 + tid;
    int v = (i < NN) ? counts[i] : 0;
    sd[tid] = v; __syncthreads();
    for (int off = 1; off < 256; off <<= 1){
        int x = sd[tid];
        int y = (tid >= off) ? sd[tid - off] : 0;
        __syncthreads();
        sd[tid] = x + y;
        __syncthreads();
    }
    if (i < NN){
        int excl = sd[tid] - v + bsum[blockIdx.x];
        row_ptr[i] = excl;
        cursor[i] = excl;
    }
    if (i == 0) row_ptr[NN] = NE;
}

__global__ void scatter_kernel(const int* __restrict__ ei,
                               int* __restrict__ cursor, int* __restrict__ csr,
                               const int* __restrict__ flags){
    int f64 = flags[1];
    int e = blockIdx.x * 256 + threadIdx.x;
    if (e < NE){
        int d = ldidx(ei, (long)NE + e, f64);
        int s = ldidx(ei, (long)e, f64);
        int pos = atomicAdd(&cursor[d], 1);
        csr[pos] = s;
    }
}

// ---------------- fused GEMM + es/ed epilogue, fp8-packed h output -------
// hq rows: 96 fp8 channels padded to 128 B stride (32 dwords).
template<int K, int H>
__global__ __launch_bounds__(256) void gemm_es_kernel(const void* __restrict__ in_,
                                                      const void* __restrict__ Wg,
                                                      const void* __restrict__ as_,
                                                      const void* __restrict__ ad_,
                                                      unsigned short* __restrict__ hq16,
                                                      float* __restrict__ es,
                                                      float* __restrict__ ed,
                                                      const int* __restrict__ flags,
                                                      int in_flex){
    constexpr int KC = 32;
    __shared__ float xs[KC][68];
    __shared__ float ws[KC][96];
    int isbf = flags[0];
    int inbf = in_flex ? isbf : 0;
    int tid = threadIdx.x;
    int row0 = blockIdx.x * 64;
    int tx = tid & 15, ty = tid >> 4;     // cols tx*6..+5, rows ty*4..+3
    float acc[4][6] = {};

    for (int k0 = 0; k0 < K; k0 += KC){
        {
            int r = tid >> 2, kb = (tid & 3) * 8;
            int rr = row0 + r; if (rr >= NN) rr = NN - 1;
            long base = (long)rr * K + k0 + kb;
            #pragma unroll
            for (int i = 0; i < 8; i++)
                xs[kb + i][r] = ldflex(in_, base + i, inbf);
        }
        for (int i = tid; i < KC * 96; i += 256){
            int kk = i / 96, cc = i - kk * 96;
            ws[kk][cc] = ldflex(Wg, (long)(k0 + kk) * 96 + cc, isbf);
        }
        __syncthreads();
        #pragma unroll 4
        for (int k = 0; k < KC; k++){
            float xr[4], wr[6];
            #pragma unroll
            for (int i = 0; i < 4; i++) xr[i] = xs[k][ty * 4 + i];
            #pragma unroll
            for (int j = 0; j < 6; j++) wr[j] = ws[k][tx * 6 + j];
            #pragma unroll
            for (int i = 0; i < 4; i++)
                #pragma unroll
                for (int j = 0; j < 6; j++)
                    acc[i][j] += xr[i] * wr[j];
        }
        __syncthreads();
    }

    float pes[4] = {}, ped[4] = {};
    #pragma unroll
    for (int j = 0; j < 6; j++){
        int c = tx * 6 + j;
        float av = ldflex(as_, c, isbf);
        float dv = ldflex(ad_, c, isbf);
        #pragma unroll
        for (int i = 0; i < 4; i++){ pes[i] += acc[i][j] * av; ped[i] += acc[i][j] * dv; }
    }
    constexpr int G = (H == 2) ? 8 : 16;
    for (int off = 1; off < G; off <<= 1){
        #pragma unroll
        for (int i = 0; i < 4; i++){
            pes[i] += __shfl_xor(pes[i], off);
            ped[i] += __shfl_xor(ped[i], off);
        }
    }
    #pragma unroll
    for (int i = 0; i < 4; i++){
        int r = row0 + ty * 4 + i;
        if (r < NN){
            long o = (long)r * 64 + tx * 3;   // short index, 64 shorts per 128B row
            hq16[o + 0] = pk_fp8(acc[i][0], acc[i][1]);
            hq16[o + 1] = pk_fp8(acc[i][2], acc[i][3]);
            hq16[o + 2] = pk_fp8(acc[i][4], acc[i][5]);
            if ((tx & (G - 1)) == 0){
                int hd = tx / G;
                es[(long)r * H + hd] = pes[i];
                ed[(long)r * H + hd] = ped[i];
            }
        }
    }
}

// ---------------- attention: wave per node, fp8 rows, 2 edges/step --------
// lanes 48-63: metadata (csr + es gather + exp) one 16-edge batch ahead.
// lanes 0-23: even edges, lanes 24-47: odd edges; each lane 1 dword = 4 ch.
template<int H>
__global__ __launch_bounds__(256) void attn_kernel(const unsigned int* __restrict__ hq,
                                                   const float* __restrict__ es,
                                                   const float* __restrict__ ed,
                                                   const int* __restrict__ row_ptr,
                                                   const int* __restrict__ csr,
                                                   const void* __restrict__ bias,
                                                   float* __restrict__ out,
                                                   const int* __restrict__ flags){
    int lane = threadIdx.x & 63;
    int d = blockIdx.x * 4 + (threadIdx.x >> 6);
    if (d >= NN) return;
    int isbf = flags[0];
    int beg = row_ptr[d], deg = row_ptr[d + 1] - beg;
    float edd0 = ed[(long)d * H];
    float edd1 = (H == 2) ? ed[(long)d * H + 1] : edd0;
    int g = (lane >= 24 && lane < 48) ? 1 : 0;
    int c = lane - g * 24;                  // dword index 0..23 for gather lanes
    bool head0 = (c < 12);                  // channels 4c..4c+3 -> head = c/12
    int m = lane - 48;

    // prefetch batch 0 metadata (lanes 48-63)
    int s_nxt = 0; float p0_nxt = 0.f, p1_nxt = 0.f;
    if (lane >= 48 && m < deg){
        int sj = csr[beg + m];
        s_nxt = sj;
        p0_nxt = __expf(lrelu(es[(long)sj * H] + edd0));
        if (H == 2) p1_nxt = __expf(lrelu(es[(long)sj * H + 1] + edd1));
    }

    float acc[4] = {0.f, 0.f, 0.f, 0.f};
    float dn0 = 0.f, dn1 = 0.f;            // metadata lanes accumulate
    for (int base = 0; base < deg; base += 16){
        int s_cur = s_nxt; float p0c = p0_nxt, p1c = p1_nxt;
        dn0 += p0c; dn1 += p1c;            // nonzero only on metadata lanes
        int nb = base + 16;
        s_nxt = 0; p0_nxt = 0.f; p1_nxt = 0.f;
        if (lane >= 48 && nb + m < deg){
            int sj = csr[beg + nb + m];
            s_nxt = sj;
            p0_nxt = __expf(lrelu(es[(long)sj * H] + edd0));
            if (H == 2) p1_nxt = __expf(lrelu(es[(long)sj * H + 1] + edd1));
        }
        unsigned int v[8]; float pv[8];
        #pragma unroll
        for (int jj = 0; jj < 8; jj++){
            int sa = rdlane_i(s_cur, 48 + 2 * jj);
            int sb = rdlane_i(s_cur, 49 + 2 * jj);
            int s = g ? sb : sa;
            float pa0 = rdlane_f(p0c, 48 + 2 * jj);
            float pb0 = rdlane_f(p0c, 49 + 2 * jj);
            float p;
            if (H == 2){
                float pa1 = rdlane_f(p1c, 48 + 2 * jj);
                float pb1 = rdlane_f(p1c, 49 + 2 * jj);
                float pa = head0 ? pa0 : pa1;
                float pb = head0 ? pb0 : pb1;
                p = g ? pb : pa;
            } else {
                p = g ? pb0 : pa0;
            }
            pv[jj] = p;
            v[jj] = (lane < 48) ? hq[(unsigned)s * 32u + (unsigned)c] : 0u;
        }
        #pragma unroll
        for (int jj = 0; jj < 8; jj++){
            float f[4];
            dec_fp8x4(v[jj], f);
            float p = pv[jj];
            acc[0] += p * f[0]; acc[1] += p * f[1];
            acc[2] += p * f[2]; acc[3] += p * f[3];
        }
    }

    // reduce dn across the 16 metadata lanes
    for (int off = 1; off < 16; off <<= 1){
        dn0 += __shfl_xor(dn0, off);
        if (H == 2) dn1 += __shfl_xor(dn1, off);
    }
    float dn0_t = rdlane_f(dn0, 48);
    float dn1_t = (H == 2) ? rdlane_f(dn1, 48) : dn0_t;

    // combine the two edge groups: lane c<24 takes partner lane c+24
    float tot[4];
    #pragma unroll
    for (int k = 0; k < 4; k++) tot[k] = acc[k] + __shfl(acc[k], lane + 24);

    if (lane < 24){
        float ps0 = __expf(lrelu(es[(long)d * H] + edd0));
        float ps1 = (H == 2) ? __expf(lrelu(es[(long)d * H + 1] + edd1)) : ps0;
        float ps = head0 ? ps0 : ps1;
        float dn = (head0 ? dn0_t : dn1_t) + ps;
        float f[4];
        dec_fp8x4(hq[(unsigned)d * 32u + (unsigned)c], f);
        float4 o;
        o.x = fmaxf((tot[0] + ps * f[0]) / dn + ldflex(bias, 4 * c + 0, isbf), 0.f);
        o.y = fmaxf((tot[1] + ps * f[1]) / dn + ldflex(bias, 4 * c + 1, isbf), 0.f);
        o.z = fmaxf((tot[2] + ps * f[2]) / dn + ldflex(bias, 4 * c + 2, isbf), 0.f);
        o.w = fmaxf((tot[3] + ps * f[3]) / dn + ldflex(bias, 4 * c + 3, isbf), 0.f);
        ((float4*)out)[(long)d * 24 + c] = o;
    }
}

// ---------------- pooling ----------------
__global__ __launch_bounds__(128) void pool_kernel(const float* __restrict__ in,
                                                   const int* __restrict__ batch,
                                                   float* __restrict__ pooled,
                                                   int* __restrict__ gcnt,
                                                   const int* __restrict__ flags){
    int f64 = flags[2];
    int n0 = blockIdx.x * 128;
    if (n0 >= NN) return;
    int n1 = n0 + 128; if (n1 > NN) n1 = NN;
    int tid = threadIdx.x;
    if (tid < 96){
        int c = tid;
        float acc = 0.f;
        int curg = ldidx(batch, n0, f64);
        for (int nd = n0; nd < n1; nd++){
            int g = ldidx(batch, nd, f64);
            if (g != curg){
                atomicAdd(&pooled[curg * 96 + c], acc);
                acc = 0.f; curg = g;
            }
            acc += in[(long)nd * 96 + c];
        }
        atomicAdd(&pooled[curg * 96 + c], acc);
    } else if (tid == 96){
        int cnt = 0;
        int curg = ldidx(batch, n0, f64);
        for (int nd = n0; nd < n1; nd++){
            int g = ldidx(batch, nd, f64);
            if (g != curg){
                atomicAdd(&gcnt[curg], cnt);
                cnt = 0; curg = g;
            }
            cnt++;
        }
        atomicAdd(&gcnt[curg], cnt);
    }
}

__global__ void final_kernel(const float* __restrict__ pooled, const int* __restrict__ gcnt,
                             const void* __restrict__ Wc, const void* __restrict__ bc,
                             void* __restrict__ outp, const int* __restrict__ flags){
    int isbf = flags[0];
    int g = threadIdx.x;
    if (g >= NG) return;
    float cnt = (float)gcnt[g];
    if (cnt < 1.f) cnt = 1.f;
    float acc = 0.f;
    for (int c = 0; c < 96; c++)
        acc += (pooled[g * 96 + c] / cnt) * ldflex(Wc, c, isbf);
    acc += ldflex(bc, 0, isbf);
    float sg = 1.f / (1.f + __expf(-acc));
    if (isbf) ((unsigned short*)outp)[g] = f2bf(sg);
    else      ((float*)outp)[g] = sg;
}

extern "C" void kernel_launch(void* const* d_in, const int* in_sizes, int n_in,
                              void* d_out, int out_size, void* d_ws, size_t ws_size,
                              hipStream_t stream){
    const void* x     = d_in[0];
    const int* ei     = (const int*)d_in[1];
    const int* batch  = (const int*)d_in[3];
    const void* W[4]  = {d_in[4],  d_in[8],  d_in[12], d_in[16]};
    const void* AS[4] = {d_in[5],  d_in[9],  d_in[13], d_in[17]};
    const void* AD[4] = {d_in[6],  d_in[10], d_in[14], d_in[18]};
    const void* B[4]  = {d_in[7],  d_in[11], d_in[15], d_in[19]};
    const void* Wc    = d_in[20];
    const void* bc    = d_in[21];

    char* p = (char*)d_ws;
    auto alloc = [&](size_t bytes) -> void* {
        void* r = (void*)p;
        p += (bytes + 255) & ~(size_t)255;
        return r;
    };
    int* flags     = (int*)alloc(16);
    unsigned int* hq = (unsigned int*)alloc((size_t)NN * 128);          // fp8 rows, 128B stride
    float* buf1    = (float*)alloc((size_t)NN * 96 * 4);                // attn out (f32)
    float* es      = (float*)alloc((size_t)NN * 2 * 4);
    float* ed      = (float*)alloc((size_t)NN * 2 * 4);
    int* counts    = (int*)alloc((size_t)NN * 4);
    int* row_ptr   = (int*)alloc((size_t)(NN + 1) * 4);
    int* cursor    = (int*)alloc((size_t)NN * 4);
    int* csr       = (int*)alloc((size_t)NE * 4);
    int* bsum      = (int*)alloc((size_t)SCAN_B * 4);
    float* pooled  = (float*)alloc((size_t)NG * 96 * 4);
    int* gcnt      = (int*)alloc((size_t)NG * 4);

    detect_kernel<<<1, 64, 0, stream>>>((const unsigned short*)x, (const unsigned int*)ei,
                                        (const unsigned int*)batch, flags);

    // CSR build (by dst), reused across layers
    hipMemsetAsync(counts, 0, (size_t)NN * 4, stream);
    count_kernel<<<(NE + 255) / 256, 256, 0, stream>>>(ei, counts, flags);
    scan_part<<<SCAN_B, 256, 0, stream>>>(counts, bsum);
    scan_mid<<<1, 256, 0, stream>>>(bsum);
    scan_final<<<SCAN_B, 256, 0, stream>>>(counts, bsum, row_ptr, cursor);
    scatter_kernel<<<(NE + 255) / 256, 256, 0, stream>>>(ei, cursor, csr, flags);

    const int GB = (NN + 63) / 64;        // 782
    const int AB = (NN + 3) / 4;          // 12500

    // layer 1 (H=2, K=128, input may be bf16-flex)
    gemm_es_kernel<128, 2><<<GB, 256, 0, stream>>>(x, W[0], AS[0], AD[0],
                                                   (unsigned short*)hq, es, ed, flags, 1);
    attn_kernel<2><<<AB, 256, 0, stream>>>(hq, es, ed, row_ptr, csr, B[0], buf1, flags);
    // layers 2..4 (H=1, K=96)
    for (int l = 1; l < 4; l++){
        gemm_es_kernel<96, 1><<<GB, 256, 0, stream>>>(buf1, W[l], AS[l], AD[l],
                                                      (unsigned short*)hq, es, ed, flags, 0);
        attn_kernel<1><<<AB, 256, 0, stream>>>(hq, es, ed, row_ptr, csr, B[l], buf1, flags);
    }

    hipMemsetAsync(pooled, 0, (size_t)NG * 96 * 4, stream);
    hipMemsetAsync(gcnt, 0, (size_t)NG * 4, stream);
    pool_kernel<<<(NN + 127) / 128, 128, 0, stream>>>(buf1, batch, pooled, gcnt, flags);
    final_kernel<<<1, 64, 0, stream>>>(pooled, gcnt, Wc, bc, d_out, flags);
}